// Round 10
// baseline (810.956 us; speedup 1.0000x reference)
//
#include <hip/hip_runtime.h>
#include <hip/hip_bf16.h>
#include <hip/hip_fp16.h>
#include <math.h>

#define IN_DIM 128
#define HID    256
#define OUTD   32
#define HEADS  4
#define NB_SH  7               // 128 dst nodes per bucket
#define BUCKET_CAP 6144        // max edges per bucket (avg ~4224)
#define NCHUNK_BLKS 256        // blocks for hist/partition phases

typedef __attribute__((ext_vector_type(8))) short s8v;
typedef __attribute__((ext_vector_type(4))) float f4v;

__device__ inline unsigned short f2bf(float f) {
    union { __hip_bfloat16 b; unsigned short u; } cv;
    cv.b = __float2bfloat16(f);
    return cv.u;
}

// ================= CSR build (bucketed, write-friendly) =================

__global__ __launch_bounds__(256) void csr_hist(const int* __restrict__ ei,
                                                int* __restrict__ H,
                                                int E, int N, int NB, int per_blk) {
    __shared__ int hist[512];
    int t = threadIdx.x;
    for (int i = t; i < NB; i += 256) hist[i] = 0;
    __syncthreads();
    int lo = blockIdx.x * per_blk;
    int hi = min(lo + per_blk, E + N);
    for (int e = lo + t; e < hi; e += 256) {
        int dst = (e < E) ? ei[E + e] : (e - E);
        atomicAdd(&hist[dst >> NB_SH], 1);
    }
    __syncthreads();
    for (int i = t; i < NB; i += 256) H[blockIdx.x * NB + i] = hist[i];
}

__global__ __launch_bounds__(256) void csr_colscan(int* __restrict__ H,
                                                   int* __restrict__ total, int NB) {
    int b = blockIdx.x, t = threadIdx.x;
    int v = H[t * NB + b];
    __shared__ int s[256];
    s[t] = v;
    __syncthreads();
    for (int o = 1; o < 256; o <<= 1) {
        int x = (t >= o) ? s[t - o] : 0;
        __syncthreads();
        s[t] += x;
        __syncthreads();
    }
    H[t * NB + b] = s[t] - v;
    if (t == 255) total[b] = s[255];
}

__global__ void csr_basescan(const int* __restrict__ total, int* __restrict__ base, int NB) {
    __shared__ int s[512];
    int t = threadIdx.x;
    int v = (t < NB) ? total[t] : 0;
    s[t] = v;
    __syncthreads();
    for (int o = 1; o < 512; o <<= 1) {
        int x = (t >= o) ? s[t - o] : 0;
        __syncthreads();
        s[t] += x;
        __syncthreads();
    }
    if (t < NB) base[t] = s[t] - v;
    if (t == NB - 1) base[NB] = s[t];
}

// packed edge: src (16 bits, N<65536) | (dst&127) << 16
__global__ __launch_bounds__(256) void csr_partition(const int* __restrict__ ei,
                                                     const int* __restrict__ H,
                                                     const int* __restrict__ base,
                                                     int* __restrict__ ebuf,
                                                     int E, int N, int per_blk, int NB) {
    __shared__ int cur[512];
    int t = threadIdx.x;
    for (int i = t; i < NB; i += 256) cur[i] = base[i] + H[blockIdx.x * NB + i];
    __syncthreads();
    int lo = blockIdx.x * per_blk;
    int hi = min(lo + per_blk, E + N);
    for (int e = lo + t; e < hi; e += 256) {
        int src = (e < E) ? ei[e] : (e - E);
        int dst = (e < E) ? ei[E + e] : (e - E);
        int pos = atomicAdd(&cur[dst >> NB_SH], 1);
        ebuf[pos] = src | ((dst & 127) << 16);
    }
}

__global__ __launch_bounds__(256) void csr_sort(const int* __restrict__ ebuf,
                                                const int* __restrict__ base,
                                                int* __restrict__ col,
                                                int* __restrict__ rp, int N, int NB) {
    int b = blockIdx.x, t = threadIdx.x;
    int lo = base[b], hi = base[b + 1];
    int nbase = b << NB_SH;
    __shared__ int c_[128], sc[128], cur[128];
    __shared__ int loc[BUCKET_CAP];
    if (t < 128) c_[t] = 0;
    __syncthreads();
    for (int k = lo + t; k < hi; k += 256) atomicAdd(&c_[(ebuf[k] >> 16) & 127], 1);
    __syncthreads();
    if (t < 128) sc[t] = c_[t];
    __syncthreads();
    for (int o = 1; o < 128; o <<= 1) {
        int x = 0;
        if (t < 128 && t >= o) x = sc[t - o];
        __syncthreads();
        if (t < 128) sc[t] += x;
        __syncthreads();
    }
    if (t < 128) {
        int excl = sc[t] - c_[t];
        cur[t] = excl;
        int node = nbase + t;
        if (node < N) rp[node] = lo + excl;
    }
    if (b == NB - 1 && t == 0) rp[N] = hi;
    __syncthreads();
    for (int k = lo + t; k < hi; k += 256) {
        int e = ebuf[k];
        int p = atomicAdd(&cur[(e >> 16) & 127], 1);
        if (p < BUCKET_CAP) loc[p] = e & 0xFFFF;
    }
    __syncthreads();
    int m = min(hi - lo, BUCKET_CAP);
    for (int k = t; k < m; k += 256) col[lo + k] = loc[k];
}

// ================= prep: f32 -> hi/lo bf16 =================

__global__ __launch_bounds__(256) void prep_w(const float* __restrict__ W,
                                              unsigned short* __restrict__ Wt_h,
                                              unsigned short* __restrict__ Wt_l,
                                              int K, int N) {
    int idx = blockIdx.x * 256 + threadIdx.x;
    if (idx >= K * N) return;
    int n = idx / K, k = idx % K;
    float x = W[(size_t)k * N + n];
    unsigned short h = f2bf(x);
    float hf = __uint_as_float((unsigned)h << 16);
    Wt_h[idx] = h;
    Wt_l[idx] = f2bf(x - hf);
}

__global__ __launch_bounds__(256) void prep_x(const float* __restrict__ X,
                                              unsigned short* __restrict__ Xh,
                                              unsigned short* __restrict__ Xl,
                                              int total8) {
    int idx = blockIdx.x * 256 + threadIdx.x;
    if (idx >= total8) return;
    size_t b = (size_t)idx * 8;
    float4 v0 = *(const float4*)(X + b);
    float4 v1 = *(const float4*)(X + b + 4);
    float x[8] = {v0.x, v0.y, v0.z, v0.w, v1.x, v1.y, v1.z, v1.w};
    union { unsigned short s[8]; uint4 q; } h, l;
#pragma unroll
    for (int j = 0; j < 8; j++) {
        h.s[j] = f2bf(x[j]);
        l.s[j] = f2bf(x[j] - __uint_as_float((unsigned)h.s[j] << 16));
    }
    *(uint4*)(Xh + b) = h.q;
    *(uint4*)(Xl + b) = l.q;
}

// ================= MFMA GEMM (hi/lo bf16 inputs) + fused scores =================
// BN=128: h stored SLICE-MAJOR hs[slice=gcol>>5][row][gcol&31] (each slice = M*64B,
// L2-fits for the slice-gather kernels). BN=32: row-major (layer 2).

template <int BN>
__global__ __launch_bounds__(256, 2) void gemm_mfma(const unsigned short* __restrict__ Ah,
                                                    const unsigned short* __restrict__ Al,
                                                    const unsigned short* __restrict__ Wt_h,
                                                    const unsigned short* __restrict__ Wt_l,
                                                    unsigned short* __restrict__ Cb,
                                                    const float* __restrict__ asrc,
                                                    const float* __restrict__ adst,
                                                    float* __restrict__ ssrcO,
                                                    float* __restrict__ sdstO,
                                                    int M, int K, int Nst, int Hn) {
    constexpr int WROWS = (BN == 128) ? 64 : 32;
    constexpr int WCOLS = (BN == 128) ? 64 : 32;
    constexpr int MI = WROWS / 16, NJ = WCOLS / 16;
    __shared__ unsigned short As_h[128][64], As_l[128][64];
    __shared__ unsigned short Bs_h[BN][64], Bs_l[BN][64];
    int tid = threadIdx.x;
    int lane = tid & 63, w = tid >> 6;
    int wm, wn;
    if (BN == 128) { wm = w & 1; wn = w >> 1; } else { wm = w; wn = 0; }
    int row0 = blockIdx.x * 128, col0 = blockIdx.y * BN;

    f4v acc[MI][NJ];
#pragma unroll
    for (int i = 0; i < MI; i++)
#pragma unroll
        for (int j = 0; j < NJ; j++) acc[i][j] = (f4v)(0.f);

    for (int k0 = 0; k0 < K; k0 += 64) {
#pragma unroll
        for (int i = 0; i < 4; i++) {
            int cidx = tid + i * 256;
            int r = cidx >> 3, ch = cidx & 7;
            int grow = row0 + r;
            uint4 vh = make_uint4(0, 0, 0, 0), vl = make_uint4(0, 0, 0, 0);
            if (grow < M) {
                size_t g = (size_t)grow * K + k0 + ch * 8;
                vh = *(const uint4*)(Ah + g);
                vl = *(const uint4*)(Al + g);
            }
            int chs = ch ^ (r & 7);
            *(uint4*)&As_h[r][chs * 8] = vh;
            *(uint4*)&As_l[r][chs * 8] = vl;
        }
#pragma unroll
        for (int i = 0; i < BN * 8 / 256; i++) {
            int cidx = tid + i * 256;
            int n = cidx >> 3, ch = cidx & 7;
            int chs = ch ^ (n & 7);
            size_t g = (size_t)(col0 + n) * K + k0 + ch * 8;
            *(uint4*)&Bs_h[n][chs * 8] = *(const uint4*)(Wt_h + g);
            *(uint4*)&Bs_l[n][chs * 8] = *(const uint4*)(Wt_l + g);
        }
        __syncthreads();
#pragma unroll
        for (int ks = 0; ks < 2; ks++) {
            s8v ah[MI], al[MI], bh[NJ], bl[NJ];
            int kc = ks * 4 + (lane >> 4);
            int lr = lane & 15;
#pragma unroll
            for (int i = 0; i < MI; i++) {
                int r = wm * WROWS + i * 16 + lr;
                ah[i] = *(const s8v*)&As_h[r][(kc ^ (r & 7)) * 8];
                al[i] = *(const s8v*)&As_l[r][(kc ^ (r & 7)) * 8];
            }
#pragma unroll
            for (int j = 0; j < NJ; j++) {
                int n = wn * WCOLS + j * 16 + lr;
                bh[j] = *(const s8v*)&Bs_h[n][(kc ^ (n & 7)) * 8];
                bl[j] = *(const s8v*)&Bs_l[n][(kc ^ (n & 7)) * 8];
            }
#pragma unroll
            for (int i = 0; i < MI; i++)
#pragma unroll
                for (int j = 0; j < NJ; j++) {
                    acc[i][j] = __builtin_amdgcn_mfma_f32_16x16x32_bf16(ah[i], bh[j], acc[i][j], 0, 0, 0);
                    acc[i][j] = __builtin_amdgcn_mfma_f32_16x16x32_bf16(ah[i], bl[j], acc[i][j], 0, 0, 0);
                    acc[i][j] = __builtin_amdgcn_mfma_f32_16x16x32_bf16(al[i], bh[j], acc[i][j], 0, 0, 0);
                }
        }
        __syncthreads();
    }
    int lr = lane & 15, lg = lane >> 4;
#pragma unroll
    for (int i = 0; i < MI; i++)
#pragma unroll
        for (int j = 0; j < NJ; j++) {
            int gcol = col0 + wn * WCOLS + j * 16 + lr;
#pragma unroll
            for (int rr = 0; rr < 4; rr++) {
                int grow = row0 + wm * WROWS + i * 16 + lg * 4 + rr;
                if (grow < M) {
                    if (BN == 128) {
                        // slice-major: hs[gcol>>5][grow][gcol&31]
                        Cb[((size_t)(gcol >> 5) * M + grow) * 32 + (gcol & 31)] =
                            f2bf(acc[i][j][rr]);
                    } else {
                        Cb[(size_t)grow * Nst + gcol] = f2bf(acc[i][j][rr]);
                    }
                }
            }
        }
    // ---- fused scores: this wave owns head hd entirely (WCOLS == D) ----
    int hd = (BN == 128) ? (blockIdx.y * 2 + wn) : 0;
    float as_[NJ], ad_[NJ];
#pragma unroll
    for (int j = 0; j < NJ; j++) {
        int gcol = col0 + wn * WCOLS + j * 16 + lr;
        as_[j] = asrc[gcol];
        ad_[j] = adst[gcol];
    }
#pragma unroll
    for (int i = 0; i < MI; i++)
#pragma unroll
        for (int rr = 0; rr < 4; rr++) {
            float ps = 0.f, pd = 0.f;
#pragma unroll
            for (int j = 0; j < NJ; j++) {
                ps += acc[i][j][rr] * as_[j];
                pd += acc[i][j][rr] * ad_[j];
            }
#pragma unroll
            for (int off = 1; off < 16; off <<= 1) {
                ps += __shfl_xor(ps, off);
                pd += __shfl_xor(pd, off);
            }
            int grow = row0 + wm * WROWS + i * 16 + lg * 4 + rr;
            if (lr == 0 && grow < M) {
                ssrcO[(size_t)grow * Hn + hd] = ps;
                sdstO[(size_t)grow * Hn + hd] = pd;
            }
        }
}

// ================= edge_alpha: segment softmax -> packed (src | alpha_fp16) =================
// One wave per node; lane = slot*4 + head. Head-major arrays colA[head][k].

__global__ __launch_bounds__(256) void edge_alpha(const float* __restrict__ ssrc,
                                                  const float* __restrict__ sdst,
                                                  const int* __restrict__ rp,
                                                  const int* __restrict__ col,
                                                  unsigned* __restrict__ colA,
                                                  int N, int Et) {
    int wv = threadIdx.x >> 6, lane = threadIdx.x & 63;
    int n = blockIdx.x * 4 + wv;
    if (n >= N) return;
    int k0 = __builtin_amdgcn_readfirstlane(rp[n]);
    int k1 = __builtin_amdgcn_readfirstlane(rp[n + 1]);
    int h1 = lane & 3, slot = lane >> 2;
    float sd1 = sdst[(size_t)n * 4 + h1];
    float m = -1e30f, l = 0.f;
    for (int k = k0 + slot; k < k1; k += 16) {
        int s = col[k];
        float e = ssrc[(size_t)s * 4 + h1] + sd1;
        e = (e > 0.f) ? e : 0.2f * e;
        float mn = fmaxf(m, e);
        l = l * __expf(m - mn) + __expf(e - mn);
        m = mn;
    }
#pragma unroll
    for (int off = 4; off < 64; off <<= 1) {
        float m2 = __shfl_xor(m, off), l2 = __shfl_xor(l, off);
        float mn = fmaxf(m, m2);
        l = l * __expf(m - mn) + l2 * __expf(m2 - mn);
        m = mn;
    }
    float invl = 1.f / l;
    for (int k = k0 + slot; k < k1; k += 16) {
        int s = col[k];
        float e = ssrc[(size_t)s * 4 + h1] + sd1;
        e = (e > 0.f) ? e : 0.2f * e;
        float a = __expf(e - m) * invl;
        unsigned short au = __half_as_ushort(__float2half(a));
        colA[(size_t)h1 * Et + k] = (unsigned)s | ((unsigned)au << 16);
    }
}

// ================= gather_slice: one 32-ch slice, strict L2-resident =================
// Launched once per slice (global barrier between slices keeps ws = M*64B < 4MB L2).
// Lean loop: 4B colA (src|alpha) + 64B slice gather + 8 FMA. No exp, no col.

__global__ __launch_bounds__(256) void gather_slice(const unsigned short* __restrict__ hsp,
                                                    const unsigned* __restrict__ colAh,
                                                    const int* __restrict__ rp,
                                                    const float* __restrict__ bias,
                                                    unsigned short* __restrict__ outH,
                                                    unsigned short* __restrict__ outL,
                                                    int N, int p) {
    int wv = threadIdx.x >> 6, lane = threadIdx.x & 63;
    int n = blockIdx.x * 4 + wv;
    if (n >= N) return;
    int k0 = __builtin_amdgcn_readfirstlane(rp[n]);
    int k1 = __builtin_amdgcn_readfirstlane(rp[n + 1]);
    int eo = lane >> 2;           // 16 edges in flight
    int cl = (lane & 3) * 8;      // 8 channels per lane
    float acc[8];
#pragma unroll
    for (int j = 0; j < 8; j++) acc[j] = 0.f;
    for (int k = k0; k < k1; k += 32) {
        int ka = k + eo, kb = k + 16 + eo;
        bool va = ka < k1, vb = kb < k1;
        unsigned wa = colAh[va ? ka : k0];
        unsigned wb = colAh[vb ? kb : k0];
        float aa = va ? __half2float(__ushort_as_half((unsigned short)(wa >> 16))) : 0.f;
        float ab = vb ? __half2float(__ushort_as_half((unsigned short)(wb >> 16))) : 0.f;
        uint4 ha = *(const uint4*)(hsp + (size_t)(wa & 0xFFFF) * 32 + cl);
        uint4 hc = *(const uint4*)(hsp + (size_t)(wb & 0xFFFF) * 32 + cl);
        const unsigned* pa = (const unsigned*)&ha;
        const unsigned* pb = (const unsigned*)&hc;
#pragma unroll
        for (int q = 0; q < 4; q++) {
            acc[2 * q]     += aa * __uint_as_float(pa[q] << 16)
                            + ab * __uint_as_float(pb[q] << 16);
            acc[2 * q + 1] += aa * __uint_as_float(pa[q] & 0xffff0000u)
                            + ab * __uint_as_float(pb[q] & 0xffff0000u);
        }
    }
#pragma unroll
    for (int off = 4; off < 64; off <<= 1)
#pragma unroll
        for (int j = 0; j < 8; j++) acc[j] += __shfl_xor(acc[j], off);
    if (eo != 0) return;
    int c = p * 32 + cl;
    union { unsigned short s[8]; uint4 q; } ph, pl;
#pragma unroll
    for (int j = 0; j < 8; j++) {
        float v = acc[j] + bias[c + j];
        v = (v > 0.f) ? v : expm1f(v);
        ph.s[j] = f2bf(v);
        pl.s[j] = f2bf(v - __uint_as_float((unsigned)ph.s[j] << 16));
    }
    *(uint4*)(outH + (size_t)n * 256 + c) = ph.q;
    *(uint4*)(outL + (size_t)n * 256 + c) = pl.q;
}

// ================= layer 2: fused gather (32ch, L2-fits) + log_softmax =================

__global__ __launch_bounds__(256) void gat_fused32(const unsigned short* __restrict__ hb,
                                                   const float* __restrict__ ssrc,
                                                   const float* __restrict__ sdst,
                                                   const int* __restrict__ rp,
                                                   const int* __restrict__ col,
                                                   const float* __restrict__ bias,
                                                   float* __restrict__ outF, int N) {
    const int TPE = 4, EPW = 16;
    int wv = threadIdx.x >> 6, lane = threadIdx.x & 63;
    int n = blockIdx.x * 4 + wv;
    if (n >= N) return;
    int k0 = __builtin_amdgcn_readfirstlane(rp[n]);
    int k1 = __builtin_amdgcn_readfirstlane(rp[n + 1]);

    float sd1 = sdst[n];
    float m = -1e30f, l = 0.f;
    for (int k = k0 + lane; k < k1; k += 64) {
        int s = col[k];
        float e = ssrc[s] + sd1;
        e = (e > 0.f) ? e : 0.2f * e;
        float mn = fmaxf(m, e);
        l = l * __expf(m - mn) + __expf(e - mn);
        m = mn;
    }
#pragma unroll
    for (int off = 1; off < 64; off <<= 1) {
        float m2 = __shfl_xor(m, off), l2 = __shfl_xor(l, off);
        float mn = fmaxf(m, m2);
        l = l * __expf(m - mn) + l2 * __expf(m2 - mn);
        m = mn;
    }
    float invl = 1.f / l;

    int eo = lane / TPE;
    int c = (lane % TPE) * 8;
    float acc[8];
#pragma unroll
    for (int j = 0; j < 8; j++) acc[j] = 0.f;
    for (int k = k0; k < k1; k += 2 * EPW) {
        int ka = k + eo, kb = k + EPW + eo;
        bool va = ka < k1, vb = kb < k1;
        int sa = col[va ? ka : k0], sb = col[vb ? kb : k0];
        float ea = ssrc[sa] + sd1;
        ea = (ea > 0.f) ? ea : 0.2f * ea;
        float aa = va ? __expf(ea - m) * invl : 0.f;
        float eb = ssrc[sb] + sd1;
        eb = (eb > 0.f) ? eb : 0.2f * eb;
        float ab = vb ? __expf(eb - m) * invl : 0.f;
        uint4 ha = *(const uint4*)(hb + (size_t)sa * 32 + c);
        uint4 hc = *(const uint4*)(hb + (size_t)sb * 32 + c);
        const unsigned* pa = (const unsigned*)&ha;
        const unsigned* pb = (const unsigned*)&hc;
#pragma unroll
        for (int q = 0; q < 4; q++) {
            acc[2 * q]     += aa * __uint_as_float(pa[q] << 16)
                            + ab * __uint_as_float(pb[q] << 16);
            acc[2 * q + 1] += aa * __uint_as_float(pa[q] & 0xffff0000u)
                            + ab * __uint_as_float(pb[q] & 0xffff0000u);
        }
    }
#pragma unroll
    for (int off = TPE; off < 64; off <<= 1)
#pragma unroll
        for (int j = 0; j < 8; j++) acc[j] += __shfl_xor(acc[j], off);

    float o[8];
#pragma unroll
    for (int j = 0; j < 8; j++) o[j] = acc[j] + bias[c + j];
    float mx = o[0];
#pragma unroll
    for (int j = 1; j < 8; j++) mx = fmaxf(mx, o[j]);
#pragma unroll
    for (int off = 1; off < TPE; off <<= 1) mx = fmaxf(mx, __shfl_xor(mx, off));
    float sm = 0.f;
#pragma unroll
    for (int j = 0; j < 8; j++) sm += __expf(o[j] - mx);
#pragma unroll
    for (int off = 1; off < TPE; off <<= 1) sm += __shfl_xor(sm, off);
    float lg = logf(sm) + mx;
    if (eo != 0) return;
    float4* op = (float4*)(outF + (size_t)n * 32 + c);
    op[0] = make_float4(o[0] - lg, o[1] - lg, o[2] - lg, o[3] - lg);
    op[1] = make_float4(o[4] - lg, o[5] - lg, o[6] - lg, o[7] - lg);
}

// ================= launch =================

extern "C" void kernel_launch(void* const* d_in, const int* in_sizes, int n_in,
                              void* d_out, int out_size, void* d_ws, size_t ws_size,
                              hipStream_t stream) {
    const float* x   = (const float*)d_in[0];
    const int*   ei  = (const int*)d_in[1];
    const float* W0  = (const float*)d_in[2];
    const float* b0  = (const float*)d_in[3];
    const float* as0 = (const float*)d_in[4];
    const float* ad0 = (const float*)d_in[5];
    const float* W1  = (const float*)d_in[6];
    const float* b1  = (const float*)d_in[7];
    const float* as1 = (const float*)d_in[8];
    const float* ad1 = (const float*)d_in[9];
    const float* W2  = (const float*)d_in[10];
    const float* b2  = (const float*)d_in[11];
    const float* as2 = (const float*)d_in[12];
    const float* ad2 = (const float*)d_in[13];

    int N = in_sizes[0] / IN_DIM;   // 50000
    int E = in_sizes[1] / 2;        // 1600000
    int Et = E + N;
    int NB = (N + 127) >> NB_SH;    // 391

    char* w = (char*)d_ws;
    size_t off = 0;
    auto alloc = [&](size_t bytes) -> void* {
        void* p = w + off;
        off = (off + bytes + 255) & ~(size_t)255;
        return p;
    };
    unsigned short* Qh    = (unsigned short*)alloc((size_t)N * HID * 2);
    unsigned short* Ql    = (unsigned short*)alloc((size_t)N * HID * 2);
    unsigned short* Ab    = (unsigned short*)alloc((size_t)N * HID * 2);  // slice-major h
    unsigned short* xh    = (unsigned short*)alloc((size_t)N * IN_DIM * 2);
    unsigned short* xl    = (unsigned short*)alloc((size_t)N * IN_DIM * 2);
    float*          ssrc  = (float*)alloc((size_t)N * HEADS * 4);
    float*          sdst  = (float*)alloc((size_t)N * HEADS * 4);
    int*            rp    = (int*)alloc((size_t)(N + 1) * 4);
    int*            col   = (int*)alloc((size_t)Et * 4);
    unsigned*       colA  = (unsigned*)alloc((size_t)HEADS * Et * 4);
    int*            H     = (int*)alloc((size_t)NCHUNK_BLKS * NB * 4);
    int*            total = (int*)alloc((size_t)(NB + 1) * 4);
    int*            base  = (int*)alloc((size_t)(NB + 1) * 4);
    int*            ebuf  = (int*)alloc((size_t)Et * 4);
    unsigned short* Wt0h  = (unsigned short*)alloc((size_t)IN_DIM * HID * 2);
    unsigned short* Wt0l  = (unsigned short*)alloc((size_t)IN_DIM * HID * 2);
    unsigned short* Wt1h  = (unsigned short*)alloc((size_t)HID * HID * 2);
    unsigned short* Wt1l  = (unsigned short*)alloc((size_t)HID * HID * 2);
    unsigned short* Wt2h  = (unsigned short*)alloc((size_t)HID * OUTD * 2);
    unsigned short* Wt2l  = (unsigned short*)alloc((size_t)HID * OUTD * 2);

    // ---- prep ----
    prep_w<<<(IN_DIM * HID + 255) / 256, 256, 0, stream>>>(W0, Wt0h, Wt0l, IN_DIM, HID);
    prep_w<<<(HID * HID + 255) / 256, 256, 0, stream>>>(W1, Wt1h, Wt1l, HID, HID);
    prep_w<<<(HID * OUTD + 255) / 256, 256, 0, stream>>>(W2, Wt2h, Wt2l, HID, OUTD);
    int t8 = N * IN_DIM / 8;
    prep_x<<<(t8 + 255) / 256, 256, 0, stream>>>(x, xh, xl, t8);

    // ---- CSR build ----
    int per_blk = (Et + NCHUNK_BLKS - 1) / NCHUNK_BLKS;
    csr_hist<<<NCHUNK_BLKS, 256, 0, stream>>>(ei, H, E, N, NB, per_blk);
    csr_colscan<<<NB, 256, 0, stream>>>(H, total, NB);
    csr_basescan<<<1, 512, 0, stream>>>(total, base, NB);
    csr_partition<<<NCHUNK_BLKS, 256, 0, stream>>>(ei, H, base, ebuf, E, N, per_blk, NB);
    csr_sort<<<NB, 256, 0, stream>>>(ebuf, base, col, rp, N, NB);

    dim3 gm((N + 127) / 128, 2);
    dim3 gm2((N + 127) / 128, 1);
    int gg = (N + 3) / 4;

    // ---- Layer 0 ----
    gemm_mfma<128><<<gm, 256, 0, stream>>>(xh, xl, Wt0h, Wt0l, Ab, as0, ad0, ssrc, sdst,
                                           N, IN_DIM, HID, HEADS);
    edge_alpha<<<gg, 256, 0, stream>>>(ssrc, sdst, rp, col, colA, N, Et);
    for (int p = 0; p < 8; p++)
        gather_slice<<<gg, 256, 0, stream>>>(Ab + (size_t)p * N * 32,
                                             colA + (size_t)(p >> 1) * Et,
                                             rp, b0, Qh, Ql, N, p);

    // ---- Layer 1 ----
    gemm_mfma<128><<<gm, 256, 0, stream>>>(Qh, Ql, Wt1h, Wt1l, Ab, as1, ad1, ssrc, sdst,
                                           N, HID, HID, HEADS);
    edge_alpha<<<gg, 256, 0, stream>>>(ssrc, sdst, rp, col, colA, N, Et);
    for (int p = 0; p < 8; p++)
        gather_slice<<<gg, 256, 0, stream>>>(Ab + (size_t)p * N * 32,
                                             colA + (size_t)(p >> 1) * Et,
                                             rp, b1, Qh, Ql, N, p);

    // ---- Layer 2 ----
    gemm_mfma<32><<<gm2, 256, 0, stream>>>(Qh, Ql, Wt2h, Wt2l, Ab, as2, ad2, ssrc, sdst,
                                           N, HID, OUTD, 1);
    gat_fused32<<<gg, 256, 0, stream>>>(Ab, ssrc, sdst, rp, col, b2, (float*)d_out, N);
}

// Round 11
// 479.000 us; speedup vs baseline: 1.6930x; 1.6930x over previous
//
#include <hip/hip_runtime.h>
#include <hip/hip_bf16.h>
#include <math.h>

#define IN_DIM 128
#define HID    256
#define OUTD   32
#define HEADS  4
#define NB_SH  7               // 128 dst nodes per bucket
#define BUCKET_CAP 6144        // max edges per bucket (avg ~4224)
#define NCHUNK_BLKS 256        // blocks for hist/partition phases

typedef __attribute__((ext_vector_type(8))) short s8v;
typedef __attribute__((ext_vector_type(4))) float f4v;

__device__ inline unsigned short f2bf(float f) {
    union { __hip_bfloat16 b; unsigned short u; } cv;
    cv.b = __float2bfloat16(f);
    return cv.u;
}

// ================= CSR build (bucketed, write-friendly) =================

__global__ __launch_bounds__(256) void csr_hist(const int* __restrict__ ei,
                                                int* __restrict__ H,
                                                int E, int N, int NB, int per_blk) {
    __shared__ int hist[512];
    int t = threadIdx.x;
    for (int i = t; i < NB; i += 256) hist[i] = 0;
    __syncthreads();
    int lo = blockIdx.x * per_blk;
    int hi = min(lo + per_blk, E + N);
    for (int e = lo + t; e < hi; e += 256) {
        int dst = (e < E) ? ei[E + e] : (e - E);
        atomicAdd(&hist[dst >> NB_SH], 1);
    }
    __syncthreads();
    for (int i = t; i < NB; i += 256) H[blockIdx.x * NB + i] = hist[i];
}

__global__ __launch_bounds__(256) void csr_colscan(int* __restrict__ H,
                                                   int* __restrict__ total, int NB) {
    int b = blockIdx.x, t = threadIdx.x;
    int v = H[t * NB + b];
    __shared__ int s[256];
    s[t] = v;
    __syncthreads();
    for (int o = 1; o < 256; o <<= 1) {
        int x = (t >= o) ? s[t - o] : 0;
        __syncthreads();
        s[t] += x;
        __syncthreads();
    }
    H[t * NB + b] = s[t] - v;
    if (t == 255) total[b] = s[255];
}

__global__ void csr_basescan(const int* __restrict__ total, int* __restrict__ base, int NB) {
    __shared__ int s[512];
    int t = threadIdx.x;
    int v = (t < NB) ? total[t] : 0;
    s[t] = v;
    __syncthreads();
    for (int o = 1; o < 512; o <<= 1) {
        int x = (t >= o) ? s[t - o] : 0;
        __syncthreads();
        s[t] += x;
        __syncthreads();
    }
    if (t < NB) base[t] = s[t] - v;
    if (t == NB - 1) base[NB] = s[t];
}

// packed edge: src (16 bits, N<65536) | (dst&127) << 16
__global__ __launch_bounds__(256) void csr_partition(const int* __restrict__ ei,
                                                     const int* __restrict__ H,
                                                     const int* __restrict__ base,
                                                     int* __restrict__ ebuf,
                                                     int E, int N, int per_blk, int NB) {
    __shared__ int cur[512];
    int t = threadIdx.x;
    for (int i = t; i < NB; i += 256) cur[i] = base[i] + H[blockIdx.x * NB + i];
    __syncthreads();
    int lo = blockIdx.x * per_blk;
    int hi = min(lo + per_blk, E + N);
    for (int e = lo + t; e < hi; e += 256) {
        int src = (e < E) ? ei[e] : (e - E);
        int dst = (e < E) ? ei[E + e] : (e - E);
        int pos = atomicAdd(&cur[dst >> NB_SH], 1);
        ebuf[pos] = src | ((dst & 127) << 16);
    }
}

__global__ __launch_bounds__(256) void csr_sort(const int* __restrict__ ebuf,
                                                const int* __restrict__ base,
                                                int* __restrict__ col,
                                                int* __restrict__ rp, int N, int NB) {
    int b = blockIdx.x, t = threadIdx.x;
    int lo = base[b], hi = base[b + 1];
    int nbase = b << NB_SH;
    __shared__ int c_[128], sc[128], cur[128];
    __shared__ int loc[BUCKET_CAP];
    if (t < 128) c_[t] = 0;
    __syncthreads();
    for (int k = lo + t; k < hi; k += 256) atomicAdd(&c_[(ebuf[k] >> 16) & 127], 1);
    __syncthreads();
    if (t < 128) sc[t] = c_[t];
    __syncthreads();
    for (int o = 1; o < 128; o <<= 1) {
        int x = 0;
        if (t < 128 && t >= o) x = sc[t - o];
        __syncthreads();
        if (t < 128) sc[t] += x;
        __syncthreads();
    }
    if (t < 128) {
        int excl = sc[t] - c_[t];
        cur[t] = excl;
        int node = nbase + t;
        if (node < N) rp[node] = lo + excl;
    }
    if (b == NB - 1 && t == 0) rp[N] = hi;
    __syncthreads();
    for (int k = lo + t; k < hi; k += 256) {
        int e = ebuf[k];
        int p = atomicAdd(&cur[(e >> 16) & 127], 1);
        if (p < BUCKET_CAP) loc[p] = e & 0xFFFF;
    }
    __syncthreads();
    int m = min(hi - lo, BUCKET_CAP);
    for (int k = t; k < m; k += 256) col[lo + k] = loc[k];
}

// ================= prep: f32 -> hi/lo bf16 =================

__global__ __launch_bounds__(256) void prep_w(const float* __restrict__ W,
                                              unsigned short* __restrict__ Wt_h,
                                              unsigned short* __restrict__ Wt_l,
                                              int K, int N) {
    int idx = blockIdx.x * 256 + threadIdx.x;
    if (idx >= K * N) return;
    int n = idx / K, k = idx % K;
    float x = W[(size_t)k * N + n];
    unsigned short h = f2bf(x);
    float hf = __uint_as_float((unsigned)h << 16);
    Wt_h[idx] = h;
    Wt_l[idx] = f2bf(x - hf);
}

__global__ __launch_bounds__(256) void prep_x(const float* __restrict__ X,
                                              unsigned short* __restrict__ Xh,
                                              unsigned short* __restrict__ Xl,
                                              int total8) {
    int idx = blockIdx.x * 256 + threadIdx.x;
    if (idx >= total8) return;
    size_t b = (size_t)idx * 8;
    float4 v0 = *(const float4*)(X + b);
    float4 v1 = *(const float4*)(X + b + 4);
    float x[8] = {v0.x, v0.y, v0.z, v0.w, v1.x, v1.y, v1.z, v1.w};
    union { unsigned short s[8]; uint4 q; } h, l;
#pragma unroll
    for (int j = 0; j < 8; j++) {
        h.s[j] = f2bf(x[j]);
        l.s[j] = f2bf(x[j] - __uint_as_float((unsigned)h.s[j] << 16));
    }
    *(uint4*)(Xh + b) = h.q;
    *(uint4*)(Xl + b) = l.q;
}

// ================= MFMA GEMM (hi/lo bf16) + fused scores =================
// A staged in LDS (32 KB); B fragments read DIRECTLY from global (weights are
// <=256 KB, L2-resident, shared by all blocks) -> 4 blocks/CU instead of 2.

template <int BN>
__global__ __launch_bounds__(256, 4) void gemm_mfma(const unsigned short* __restrict__ Ah,
                                                    const unsigned short* __restrict__ Al,
                                                    const unsigned short* __restrict__ Wt_h,
                                                    const unsigned short* __restrict__ Wt_l,
                                                    unsigned short* __restrict__ Cb,
                                                    const float* __restrict__ asrc,
                                                    const float* __restrict__ adst,
                                                    float* __restrict__ ssrcO,
                                                    float* __restrict__ sdstO,
                                                    int M, int K, int Nst, int Hn) {
    constexpr int WROWS = (BN == 128) ? 64 : 32;
    constexpr int WCOLS = (BN == 128) ? 64 : 32;
    constexpr int MI = WROWS / 16, NJ = WCOLS / 16;
    __shared__ unsigned short As_h[128][64], As_l[128][64];   // 32 KB
    int tid = threadIdx.x;
    int lane = tid & 63, w = tid >> 6;
    int wm, wn;
    if (BN == 128) { wm = w & 1; wn = w >> 1; } else { wm = w; wn = 0; }
    int row0 = blockIdx.x * 128, col0 = blockIdx.y * BN;
    int lr = lane & 15;

    // B row base offsets (row-major transposed weights: Wt[n][k])
    unsigned brow[NJ];
#pragma unroll
    for (int j = 0; j < NJ; j++)
        brow[j] = (unsigned)(col0 + wn * WCOLS + j * 16 + lr) * (unsigned)K;

    f4v acc[MI][NJ];
#pragma unroll
    for (int i = 0; i < MI; i++)
#pragma unroll
        for (int j = 0; j < NJ; j++) acc[i][j] = (f4v)(0.f);

    for (int k0 = 0; k0 < K; k0 += 64) {
        // ---- stage A hi/lo (1024 16B-chunks / 256 threads = 4 each) ----
#pragma unroll
        for (int i = 0; i < 4; i++) {
            int cidx = tid + i * 256;
            int r = cidx >> 3, ch = cidx & 7;
            int grow = row0 + r;
            uint4 vh = make_uint4(0, 0, 0, 0), vl = make_uint4(0, 0, 0, 0);
            if (grow < M) {
                size_t g = (size_t)grow * K + k0 + ch * 8;
                vh = *(const uint4*)(Ah + g);
                vl = *(const uint4*)(Al + g);
            }
            int chs = ch ^ (r & 7);
            *(uint4*)&As_h[r][chs * 8] = vh;
            *(uint4*)&As_l[r][chs * 8] = vl;
        }
        __syncthreads();
#pragma unroll
        for (int ks = 0; ks < 2; ks++) {
            int kc = ks * 4 + (lane >> 4);
            s8v ah[MI], al[MI], bh[NJ], bl[NJ];
            unsigned koff = (unsigned)(k0 + kc * 8);
#pragma unroll
            for (int j = 0; j < NJ; j++) {
                bh[j] = *(const s8v*)(Wt_h + brow[j] + koff);
                bl[j] = *(const s8v*)(Wt_l + brow[j] + koff);
            }
#pragma unroll
            for (int i = 0; i < MI; i++) {
                int r = wm * WROWS + i * 16 + lr;
                ah[i] = *(const s8v*)&As_h[r][(kc ^ (r & 7)) * 8];
                al[i] = *(const s8v*)&As_l[r][(kc ^ (r & 7)) * 8];
            }
#pragma unroll
            for (int i = 0; i < MI; i++)
#pragma unroll
                for (int j = 0; j < NJ; j++) {
                    acc[i][j] = __builtin_amdgcn_mfma_f32_16x16x32_bf16(ah[i], bh[j], acc[i][j], 0, 0, 0);
                    acc[i][j] = __builtin_amdgcn_mfma_f32_16x16x32_bf16(ah[i], bl[j], acc[i][j], 0, 0, 0);
                    acc[i][j] = __builtin_amdgcn_mfma_f32_16x16x32_bf16(al[i], bh[j], acc[i][j], 0, 0, 0);
                }
        }
        __syncthreads();
    }
    int lg = lane >> 4;
#pragma unroll
    for (int i = 0; i < MI; i++)
#pragma unroll
        for (int j = 0; j < NJ; j++) {
            int gcol = col0 + wn * WCOLS + j * 16 + lr;
#pragma unroll
            for (int rr = 0; rr < 4; rr++) {
                int grow = row0 + wm * WROWS + i * 16 + lg * 4 + rr;
                if (grow < M) Cb[(size_t)grow * Nst + gcol] = f2bf(acc[i][j][rr]);
            }
        }
    // ---- fused scores: this wave owns head hd entirely (WCOLS == D) ----
    int hd = (BN == 128) ? (blockIdx.y * 2 + wn) : 0;
    float as_[NJ], ad_[NJ];
#pragma unroll
    for (int j = 0; j < NJ; j++) {
        int gcol = col0 + wn * WCOLS + j * 16 + lr;
        as_[j] = asrc[gcol];
        ad_[j] = adst[gcol];
    }
#pragma unroll
    for (int i = 0; i < MI; i++)
#pragma unroll
        for (int rr = 0; rr < 4; rr++) {
            float ps = 0.f, pd = 0.f;
#pragma unroll
            for (int j = 0; j < NJ; j++) {
                ps += acc[i][j][rr] * as_[j];
                pd += acc[i][j][rr] * ad_[j];
            }
#pragma unroll
            for (int off = 1; off < 16; off <<= 1) {
                ps += __shfl_xor(ps, off);
                pd += __shfl_xor(pd, off);
            }
            int grow = row0 + wm * WROWS + i * 16 + lg * 4 + rr;
            if (lr == 0 && grow < M) {
                ssrcO[(size_t)grow * Hn + hd] = ps;
                sdstO[(size_t)grow * Hn + hd] = pd;
            }
        }
}

// ================= fused segment-softmax + weighted gather (R8 form) =================

template <int CH, int H, int MODE, int UNR>
__global__ __launch_bounds__(256) void gat_fused(const unsigned short* __restrict__ hb,
                                                 const float* __restrict__ ssrc,
                                                 const float* __restrict__ sdst,
                                                 const int* __restrict__ rp,
                                                 const int* __restrict__ col,
                                                 const float* __restrict__ bias,
                                                 float* __restrict__ outF,
                                                 unsigned short* __restrict__ outH,
                                                 unsigned short* __restrict__ outL, int N) {
    const int TPE = CH / 8;
    const int EPW = 64 / TPE;
    const int D = CH / H;
    constexpr int SHCH = (CH == 256) ? 9 : 6;
    constexpr int SHS = (H == 4) ? 4 : 2;
    int wv = threadIdx.x >> 6, lane = threadIdx.x & 63;
    int n = blockIdx.x * 4 + wv;
    if (n >= N) return;
    int k0 = __builtin_amdgcn_readfirstlane(rp[n]);
    int k1 = __builtin_amdgcn_readfirstlane(rp[n + 1]);

    int h1 = lane % H;
    int slot = lane / H;
    const int SL = 64 / H;
    float sd1 = sdst[(size_t)n * H + h1];
    float m = -1e30f, l = 0.f;
    for (int k = k0 + slot; k < k1; k += SL) {
        int s = col[k];
        float e = ssrc[(size_t)s * H + h1] + sd1;
        e = (e > 0.f) ? e : 0.2f * e;
        float mn = fmaxf(m, e);
        l = l * __expf(m - mn) + __expf(e - mn);
        m = mn;
    }
#pragma unroll
    for (int off = H; off < 64; off <<= 1) {
        float m2 = __shfl_xor(m, off);
        float l2 = __shfl_xor(l, off);
        float mn = fmaxf(m, m2);
        l = l * __expf(m - mn) + l2 * __expf(m2 - mn);
        m = mn;
    }

    int eo = lane / TPE;
    int c = (lane % TPE) * 8;
    int head = c / D;
    float mh = __shfl(m, head);
    float invl = 1.f / __shfl(l, head);
    float sdh = __shfl(sd1, head);

    const char* hbc = (const char*)hb;
    const char* ssc = (const char*)ssrc;
    unsigned cb = (unsigned)(c << 1);
    unsigned hb4 = (unsigned)(head << 2);

    float acc[8];
#pragma unroll
    for (int j = 0; j < 8; j++) acc[j] = 0.f;

    for (int k = k0; k < k1; k += UNR * EPW) {
        int ss[UNR];
        float aa[UNR];
#pragma unroll
        for (int u = 0; u < UNR; u++) {
            int ku = k + u * EPW + eo;
            bool v = ku < k1;
            ss[u] = col[v ? ku : k0];
            aa[u] = v ? invl : 0.f;
        }
        uint4 hv[UNR];
#pragma unroll
        for (int u = 0; u < UNR; u++)
            hv[u] = *(const uint4*)(hbc + (((unsigned)ss[u] << SHCH) + cb));
#pragma unroll
        for (int u = 0; u < UNR; u++) {
            float e = *(const float*)(ssc + (((unsigned)ss[u] << SHS) + hb4)) + sdh;
            e = (e > 0.f) ? e : 0.2f * e;
            aa[u] *= __expf(e - mh);
        }
#pragma unroll
        for (int u = 0; u < UNR; u++) {
            const unsigned* p = (const unsigned*)&hv[u];
#pragma unroll
            for (int q = 0; q < 4; q++) {
                acc[2 * q]     += aa[u] * __uint_as_float(p[q] << 16);
                acc[2 * q + 1] += aa[u] * __uint_as_float(p[q] & 0xffff0000u);
            }
        }
    }
#pragma unroll
    for (int off = TPE; off < 64; off <<= 1)
#pragma unroll
        for (int j = 0; j < 8; j++) acc[j] += __shfl_xor(acc[j], off);

    float o[8];
#pragma unroll
    for (int j = 0; j < 8; j++) o[j] = acc[j] + bias[c + j];
    if (MODE == 1) {
        float mx = o[0];
#pragma unroll
        for (int j = 1; j < 8; j++) mx = fmaxf(mx, o[j]);
#pragma unroll
        for (int off = 1; off < TPE; off <<= 1) mx = fmaxf(mx, __shfl_xor(mx, off));
        float sm = 0.f;
#pragma unroll
        for (int j = 0; j < 8; j++) sm += __expf(o[j] - mx);
#pragma unroll
        for (int off = 1; off < TPE; off <<= 1) sm += __shfl_xor(sm, off);
        float lg = logf(sm) + mx;
        if (eo != 0) return;
        float4* op = (float4*)(outF + (size_t)n * CH + c);
        op[0] = make_float4(o[0] - lg, o[1] - lg, o[2] - lg, o[3] - lg);
        op[1] = make_float4(o[4] - lg, o[5] - lg, o[6] - lg, o[7] - lg);
    } else {
        if (eo != 0) return;
        union { unsigned short s[8]; uint4 q; } ph, pl;
#pragma unroll
        for (int j = 0; j < 8; j++) {
            float v = (o[j] > 0.f) ? o[j] : expm1f(o[j]);
            ph.s[j] = f2bf(v);
            pl.s[j] = f2bf(v - __uint_as_float((unsigned)ph.s[j] << 16));
        }
        *(uint4*)(outH + (size_t)n * CH + c) = ph.q;
        *(uint4*)(outL + (size_t)n * CH + c) = pl.q;
    }
}

// ================= launch =================

extern "C" void kernel_launch(void* const* d_in, const int* in_sizes, int n_in,
                              void* d_out, int out_size, void* d_ws, size_t ws_size,
                              hipStream_t stream) {
    const float* x   = (const float*)d_in[0];
    const int*   ei  = (const int*)d_in[1];
    const float* W0  = (const float*)d_in[2];
    const float* b0  = (const float*)d_in[3];
    const float* as0 = (const float*)d_in[4];
    const float* ad0 = (const float*)d_in[5];
    const float* W1  = (const float*)d_in[6];
    const float* b1  = (const float*)d_in[7];
    const float* as1 = (const float*)d_in[8];
    const float* ad1 = (const float*)d_in[9];
    const float* W2  = (const float*)d_in[10];
    const float* b2  = (const float*)d_in[11];
    const float* as2 = (const float*)d_in[12];
    const float* ad2 = (const float*)d_in[13];

    int N = in_sizes[0] / IN_DIM;   // 50000
    int E = in_sizes[1] / 2;        // 1600000
    int Et = E + N;
    int NB = (N + 127) >> NB_SH;    // 391

    char* w = (char*)d_ws;
    size_t off = 0;
    auto alloc = [&](size_t bytes) -> void* {
        void* p = w + off;
        off = (off + bytes + 255) & ~(size_t)255;
        return p;
    };
    unsigned short* Qh    = (unsigned short*)alloc((size_t)N * HID * 2);
    unsigned short* Ql    = (unsigned short*)alloc((size_t)N * HID * 2);
    unsigned short* Ab    = (unsigned short*)alloc((size_t)N * HID * 2);
    unsigned short* xh    = (unsigned short*)alloc((size_t)N * IN_DIM * 2);
    unsigned short* xl    = (unsigned short*)alloc((size_t)N * IN_DIM * 2);
    float*          ssrc  = (float*)alloc((size_t)N * HEADS * 4);
    float*          sdst  = (float*)alloc((size_t)N * HEADS * 4);
    int*            rp    = (int*)alloc((size_t)(N + 1) * 4);
    int*            col   = (int*)alloc((size_t)Et * 4);
    int*            H     = (int*)alloc((size_t)NCHUNK_BLKS * NB * 4);
    int*            total = (int*)alloc((size_t)(NB + 1) * 4);
    int*            base  = (int*)alloc((size_t)(NB + 1) * 4);
    int*            ebuf  = (int*)alloc((size_t)Et * 4);
    unsigned short* Wt0h  = (unsigned short*)alloc((size_t)IN_DIM * HID * 2);
    unsigned short* Wt0l  = (unsigned short*)alloc((size_t)IN_DIM * HID * 2);
    unsigned short* Wt1h  = (unsigned short*)alloc((size_t)HID * HID * 2);
    unsigned short* Wt1l  = (unsigned short*)alloc((size_t)HID * HID * 2);
    unsigned short* Wt2h  = (unsigned short*)alloc((size_t)HID * OUTD * 2);
    unsigned short* Wt2l  = (unsigned short*)alloc((size_t)HID * OUTD * 2);

    // ---- prep ----
    prep_w<<<(IN_DIM * HID + 255) / 256, 256, 0, stream>>>(W0, Wt0h, Wt0l, IN_DIM, HID);
    prep_w<<<(HID * HID + 255) / 256, 256, 0, stream>>>(W1, Wt1h, Wt1l, HID, HID);
    prep_w<<<(HID * OUTD + 255) / 256, 256, 0, stream>>>(W2, Wt2h, Wt2l, HID, OUTD);
    int t8 = N * IN_DIM / 8;
    prep_x<<<(t8 + 255) / 256, 256, 0, stream>>>(x, xh, xl, t8);

    // ---- CSR build ----
    int per_blk = (Et + NCHUNK_BLKS - 1) / NCHUNK_BLKS;
    csr_hist<<<NCHUNK_BLKS, 256, 0, stream>>>(ei, H, E, N, NB, per_blk);
    csr_colscan<<<NB, 256, 0, stream>>>(H, total, NB);
    csr_basescan<<<1, 512, 0, stream>>>(total, base, NB);
    csr_partition<<<NCHUNK_BLKS, 256, 0, stream>>>(ei, H, base, ebuf, E, N, per_blk, NB);
    csr_sort<<<NB, 256, 0, stream>>>(ebuf, base, col, rp, N, NB);

    dim3 gm((N + 127) / 128, 2);
    dim3 gm2((N + 127) / 128, 1);
    int gg = (N + 3) / 4;

    // ---- Layer 0 ----
    gemm_mfma<128><<<gm, 256, 0, stream>>>(xh, xl, Wt0h, Wt0l, Ab, as0, ad0, ssrc, sdst,
                                           N, IN_DIM, HID, HEADS);
    gat_fused<HID, HEADS, 0, 4><<<gg, 256, 0, stream>>>(Ab, ssrc, sdst, rp, col, b0,
                                                        nullptr, Qh, Ql, N);

    // ---- Layer 1 ----
    gemm_mfma<128><<<gm, 256, 0, stream>>>(Qh, Ql, Wt1h, Wt1l, Ab, as1, ad1, ssrc, sdst,
                                           N, HID, HID, HEADS);
    gat_fused<HID, HEADS, 0, 4><<<gg, 256, 0, stream>>>(Ab, ssrc, sdst, rp, col, b1,
                                                        nullptr, Qh, Ql, N);

    // ---- Layer 2 ----
    gemm_mfma<32><<<gm2, 256, 0, stream>>>(Qh, Ql, Wt2h, Wt2l, Ab, as2, ad2, ssrc, sdst,
                                           N, HID, OUTD, 1);
    gat_fused<OUTD, 1, 1, 2><<<gg, 256, 0, stream>>>(Ab, ssrc, sdst, rp, col, b2,
                                                     (float*)d_out, nullptr, nullptr, N);
}

// Round 12
// 443.054 us; speedup vs baseline: 1.8304x; 1.0811x over previous
//
#include <hip/hip_runtime.h>
#include <hip/hip_bf16.h>
#include <math.h>

#define IN_DIM 128
#define HID    256
#define OUTD   32
#define HEADS  4
#define NB_SH  7               // 128 dst nodes per bucket
#define BUCKET_CAP 6144        // max edges per bucket (avg ~4224)
#define NCHUNK_BLKS 256        // blocks for hist/partition phases

typedef __attribute__((ext_vector_type(8))) short s8v;
typedef __attribute__((ext_vector_type(4))) float f4v;

__device__ inline unsigned short f2bf(float f) {
    union { __hip_bfloat16 b; unsigned short u; } cv;
    cv.b = __float2bfloat16(f);
    return cv.u;
}

// ================= CSR build (bucketed, write-friendly) =================

__global__ __launch_bounds__(256) void csr_hist(const int* __restrict__ ei,
                                                int* __restrict__ H,
                                                int E, int N, int NB, int per_blk) {
    __shared__ int hist[512];
    int t = threadIdx.x;
    for (int i = t; i < NB; i += 256) hist[i] = 0;
    __syncthreads();
    int lo = blockIdx.x * per_blk;
    int hi = min(lo + per_blk, E + N);
    for (int e = lo + t; e < hi; e += 256) {
        int dst = (e < E) ? ei[E + e] : (e - E);
        atomicAdd(&hist[dst >> NB_SH], 1);
    }
    __syncthreads();
    for (int i = t; i < NB; i += 256) H[blockIdx.x * NB + i] = hist[i];
}

__global__ __launch_bounds__(256) void csr_colscan(int* __restrict__ H,
                                                   int* __restrict__ total, int NB) {
    int b = blockIdx.x, t = threadIdx.x;
    int v = H[t * NB + b];
    __shared__ int s[256];
    s[t] = v;
    __syncthreads();
    for (int o = 1; o < 256; o <<= 1) {
        int x = (t >= o) ? s[t - o] : 0;
        __syncthreads();
        s[t] += x;
        __syncthreads();
    }
    H[t * NB + b] = s[t] - v;
    if (t == 255) total[b] = s[255];
}

__global__ void csr_basescan(const int* __restrict__ total, int* __restrict__ base, int NB) {
    __shared__ int s[512];
    int t = threadIdx.x;
    int v = (t < NB) ? total[t] : 0;
    s[t] = v;
    __syncthreads();
    for (int o = 1; o < 512; o <<= 1) {
        int x = (t >= o) ? s[t - o] : 0;
        __syncthreads();
        s[t] += x;
        __syncthreads();
    }
    if (t < NB) base[t] = s[t] - v;
    if (t == NB - 1) base[NB] = s[t];
}

// packed edge: src (16 bits, N<65536) | (dst&127) << 16
__global__ __launch_bounds__(256) void csr_partition(const int* __restrict__ ei,
                                                     const int* __restrict__ H,
                                                     const int* __restrict__ base,
                                                     int* __restrict__ ebuf,
                                                     int E, int N, int per_blk, int NB) {
    __shared__ int cur[512];
    int t = threadIdx.x;
    for (int i = t; i < NB; i += 256) cur[i] = base[i] + H[blockIdx.x * NB + i];
    __syncthreads();
    int lo = blockIdx.x * per_blk;
    int hi = min(lo + per_blk, E + N);
    for (int e = lo + t; e < hi; e += 256) {
        int src = (e < E) ? ei[e] : (e - E);
        int dst = (e < E) ? ei[E + e] : (e - E);
        int pos = atomicAdd(&cur[dst >> NB_SH], 1);
        ebuf[pos] = src | ((dst & 127) << 16);
    }
}

__global__ __launch_bounds__(256) void csr_sort(const int* __restrict__ ebuf,
                                                const int* __restrict__ base,
                                                int* __restrict__ col,
                                                int* __restrict__ rp, int N, int NB) {
    int b = blockIdx.x, t = threadIdx.x;
    int lo = base[b], hi = base[b + 1];
    int nbase = b << NB_SH;
    __shared__ int c_[128], sc[128], cur[128];
    __shared__ int loc[BUCKET_CAP];
    if (t < 128) c_[t] = 0;
    __syncthreads();
    for (int k = lo + t; k < hi; k += 256) atomicAdd(&c_[(ebuf[k] >> 16) & 127], 1);
    __syncthreads();
    if (t < 128) sc[t] = c_[t];
    __syncthreads();
    for (int o = 1; o < 128; o <<= 1) {
        int x = 0;
        if (t < 128 && t >= o) x = sc[t - o];
        __syncthreads();
        if (t < 128) sc[t] += x;
        __syncthreads();
    }
    if (t < 128) {
        int excl = sc[t] - c_[t];
        cur[t] = excl;
        int node = nbase + t;
        if (node < N) rp[node] = lo + excl;
    }
    if (b == NB - 1 && t == 0) rp[N] = hi;
    __syncthreads();
    for (int k = lo + t; k < hi; k += 256) {
        int e = ebuf[k];
        int p = atomicAdd(&cur[(e >> 16) & 127], 1);
        if (p < BUCKET_CAP) loc[p] = e & 0xFFFF;
    }
    __syncthreads();
    int m = min(hi - lo, BUCKET_CAP);
    for (int k = t; k < m; k += 256) col[lo + k] = loc[k];
}

// ================= prep: f32 -> hi/lo bf16 =================

__global__ __launch_bounds__(256) void prep_w(const float* __restrict__ W,
                                              unsigned short* __restrict__ Wt_h,
                                              unsigned short* __restrict__ Wt_l,
                                              int K, int N) {
    int idx = blockIdx.x * 256 + threadIdx.x;
    if (idx >= K * N) return;
    int n = idx / K, k = idx % K;
    float x = W[(size_t)k * N + n];
    unsigned short h = f2bf(x);
    float hf = __uint_as_float((unsigned)h << 16);
    Wt_h[idx] = h;
    Wt_l[idx] = f2bf(x - hf);
}

__global__ __launch_bounds__(256) void prep_x(const float* __restrict__ X,
                                              unsigned short* __restrict__ Xh,
                                              unsigned short* __restrict__ Xl,
                                              int total8) {
    int idx = blockIdx.x * 256 + threadIdx.x;
    if (idx >= total8) return;
    size_t b = (size_t)idx * 8;
    float4 v0 = *(const float4*)(X + b);
    float4 v1 = *(const float4*)(X + b + 4);
    float x[8] = {v0.x, v0.y, v0.z, v0.w, v1.x, v1.y, v1.z, v1.w};
    union { unsigned short s[8]; uint4 q; } h, l;
#pragma unroll
    for (int j = 0; j < 8; j++) {
        h.s[j] = f2bf(x[j]);
        l.s[j] = f2bf(x[j] - __uint_as_float((unsigned)h.s[j] << 16));
    }
    *(uint4*)(Xh + b) = h.q;
    *(uint4*)(Xl + b) = l.q;
}

// ================= MFMA GEMM (hi/lo bf16) + fused scores =================
// BK=32 -> 32 KB LDS/block (A 16 + B 16 for BN=128) -> ~5 blocks/CU occupancy.
// Swizzle on 16B chunks within 64B rows: chs = ch ^ ((r>>1)&3)  (2-way = free).
// Grid is (cols, rows) so both column-blocks of an A-panel are dispatch-adjacent.

template <int BN>
__global__ __launch_bounds__(256, 2) void gemm_mfma(const unsigned short* __restrict__ Ah,
                                                    const unsigned short* __restrict__ Al,
                                                    const unsigned short* __restrict__ Wt_h,
                                                    const unsigned short* __restrict__ Wt_l,
                                                    unsigned short* __restrict__ Cb,
                                                    const float* __restrict__ asrc,
                                                    const float* __restrict__ adst,
                                                    float* __restrict__ ssrcO,
                                                    float* __restrict__ sdstO,
                                                    int M, int K, int Nst, int Hn) {
    constexpr int WROWS = (BN == 128) ? 64 : 32;
    constexpr int WCOLS = (BN == 128) ? 64 : 32;
    constexpr int MI = WROWS / 16, NJ = WCOLS / 16;
    __shared__ unsigned short As_h[128][32], As_l[128][32];   // 16 KB
    __shared__ unsigned short Bs_h[BN][32], Bs_l[BN][32];     // 16 or 4 KB
    int tid = threadIdx.x;
    int lane = tid & 63, w = tid >> 6;
    int wm, wn;
    if (BN == 128) { wm = w & 1; wn = w >> 1; } else { wm = w; wn = 0; }
    int row0 = blockIdx.y * 128, col0 = blockIdx.x * BN;
    int lr = lane & 15;

    f4v acc[MI][NJ];
#pragma unroll
    for (int i = 0; i < MI; i++)
#pragma unroll
        for (int j = 0; j < NJ; j++) acc[i][j] = (f4v)(0.f);

    for (int k0 = 0; k0 < K; k0 += 32) {
        // ---- stage A: 128 rows x 4 chunks = 512 chunks, 2 per thread ----
#pragma unroll
        for (int i = 0; i < 2; i++) {
            int c = tid + i * 256;
            int r = c >> 2, ch = c & 3;
            int grow = row0 + r;
            uint4 vh = make_uint4(0, 0, 0, 0), vl = make_uint4(0, 0, 0, 0);
            if (grow < M) {
                size_t g = (size_t)grow * K + k0 + ch * 8;
                vh = *(const uint4*)(Ah + g);
                vl = *(const uint4*)(Al + g);
            }
            int chs = ch ^ ((r >> 1) & 3);
            *(uint4*)&As_h[r][chs * 8] = vh;
            *(uint4*)&As_l[r][chs * 8] = vl;
        }
        // ---- stage B: BN rows x 4 chunks ----
        for (int c = tid; c < BN * 4; c += 256) {
            int n = c >> 2, ch = c & 3;
            int chs = ch ^ ((n >> 1) & 3);
            size_t g = (size_t)(col0 + n) * K + k0 + ch * 8;
            *(uint4*)&Bs_h[n][chs * 8] = *(const uint4*)(Wt_h + g);
            *(uint4*)&Bs_l[n][chs * 8] = *(const uint4*)(Wt_l + g);
        }
        __syncthreads();
        {
            int kc = lane >> 4;   // 0..3, covers BK=32
            s8v ah[MI], al[MI], bh[NJ], bl[NJ];
#pragma unroll
            for (int i = 0; i < MI; i++) {
                int r = wm * WROWS + i * 16 + lr;
                int chs = kc ^ ((r >> 1) & 3);
                ah[i] = *(const s8v*)&As_h[r][chs * 8];
                al[i] = *(const s8v*)&As_l[r][chs * 8];
            }
#pragma unroll
            for (int j = 0; j < NJ; j++) {
                int n = wn * WCOLS + j * 16 + lr;
                int chs = kc ^ ((n >> 1) & 3);
                bh[j] = *(const s8v*)&Bs_h[n][chs * 8];
                bl[j] = *(const s8v*)&Bs_l[n][chs * 8];
            }
#pragma unroll
            for (int i = 0; i < MI; i++)
#pragma unroll
                for (int j = 0; j < NJ; j++) {
                    acc[i][j] = __builtin_amdgcn_mfma_f32_16x16x32_bf16(ah[i], bh[j], acc[i][j], 0, 0, 0);
                    acc[i][j] = __builtin_amdgcn_mfma_f32_16x16x32_bf16(ah[i], bl[j], acc[i][j], 0, 0, 0);
                    acc[i][j] = __builtin_amdgcn_mfma_f32_16x16x32_bf16(al[i], bh[j], acc[i][j], 0, 0, 0);
                }
        }
        __syncthreads();
    }
    int lg = lane >> 4;
#pragma unroll
    for (int i = 0; i < MI; i++)
#pragma unroll
        for (int j = 0; j < NJ; j++) {
            int gcol = col0 + wn * WCOLS + j * 16 + lr;
#pragma unroll
            for (int rr = 0; rr < 4; rr++) {
                int grow = row0 + wm * WROWS + i * 16 + lg * 4 + rr;
                if (grow < M) Cb[(size_t)grow * Nst + gcol] = f2bf(acc[i][j][rr]);
            }
        }
    // ---- fused scores: this wave owns head hd entirely (WCOLS == D) ----
    int hd = (BN == 128) ? (blockIdx.x * 2 + wn) : 0;
    float as_[NJ], ad_[NJ];
#pragma unroll
    for (int j = 0; j < NJ; j++) {
        int gcol = col0 + wn * WCOLS + j * 16 + lr;
        as_[j] = asrc[gcol];
        ad_[j] = adst[gcol];
    }
#pragma unroll
    for (int i = 0; i < MI; i++)
#pragma unroll
        for (int rr = 0; rr < 4; rr++) {
            float ps = 0.f, pd = 0.f;
#pragma unroll
            for (int j = 0; j < NJ; j++) {
                ps += acc[i][j][rr] * as_[j];
                pd += acc[i][j][rr] * ad_[j];
            }
#pragma unroll
            for (int off = 1; off < 16; off <<= 1) {
                ps += __shfl_xor(ps, off);
                pd += __shfl_xor(pd, off);
            }
            int grow = row0 + wm * WROWS + i * 16 + lg * 4 + rr;
            if (lr == 0 && grow < M) {
                ssrcO[(size_t)grow * Hn + hd] = ps;
                sdstO[(size_t)grow * Hn + hd] = pd;
            }
        }
}

// ================= fused segment-softmax + weighted gather (R8 form, measured 124us) =================

template <int CH, int H, int MODE, int UNR>
__global__ __launch_bounds__(256) void gat_fused(const unsigned short* __restrict__ hb,
                                                 const float* __restrict__ ssrc,
                                                 const float* __restrict__ sdst,
                                                 const int* __restrict__ rp,
                                                 const int* __restrict__ col,
                                                 const float* __restrict__ bias,
                                                 float* __restrict__ outF,
                                                 unsigned short* __restrict__ outH,
                                                 unsigned short* __restrict__ outL, int N) {
    const int TPE = CH / 8;
    const int EPW = 64 / TPE;
    const int D = CH / H;
    constexpr int SHCH = (CH == 256) ? 9 : 6;
    constexpr int SHS = (H == 4) ? 4 : 2;
    int wv = threadIdx.x >> 6, lane = threadIdx.x & 63;
    int n = blockIdx.x * 4 + wv;
    if (n >= N) return;
    int k0 = __builtin_amdgcn_readfirstlane(rp[n]);
    int k1 = __builtin_amdgcn_readfirstlane(rp[n + 1]);

    int h1 = lane % H;
    int slot = lane / H;
    const int SL = 64 / H;
    float sd1 = sdst[(size_t)n * H + h1];
    float m = -1e30f, l = 0.f;
    for (int k = k0 + slot; k < k1; k += SL) {
        int s = col[k];
        float e = ssrc[(size_t)s * H + h1] + sd1;
        e = (e > 0.f) ? e : 0.2f * e;
        float mn = fmaxf(m, e);
        l = l * __expf(m - mn) + __expf(e - mn);
        m = mn;
    }
#pragma unroll
    for (int off = H; off < 64; off <<= 1) {
        float m2 = __shfl_xor(m, off);
        float l2 = __shfl_xor(l, off);
        float mn = fmaxf(m, m2);
        l = l * __expf(m - mn) + l2 * __expf(m2 - mn);
        m = mn;
    }

    int eo = lane / TPE;
    int c = (lane % TPE) * 8;
    int head = c / D;
    float mh = __shfl(m, head);
    float invl = 1.f / __shfl(l, head);
    float sdh = __shfl(sd1, head);

    const char* hbc = (const char*)hb;
    const char* ssc = (const char*)ssrc;
    unsigned cb = (unsigned)(c << 1);
    unsigned hb4 = (unsigned)(head << 2);

    float acc[8];
#pragma unroll
    for (int j = 0; j < 8; j++) acc[j] = 0.f;

    for (int k = k0; k < k1; k += UNR * EPW) {
        int ss[UNR];
        float aa[UNR];
#pragma unroll
        for (int u = 0; u < UNR; u++) {
            int ku = k + u * EPW + eo;
            bool v = ku < k1;
            ss[u] = col[v ? ku : k0];
            aa[u] = v ? invl : 0.f;
        }
        uint4 hv[UNR];
#pragma unroll
        for (int u = 0; u < UNR; u++)
            hv[u] = *(const uint4*)(hbc + (((unsigned)ss[u] << SHCH) + cb));
#pragma unroll
        for (int u = 0; u < UNR; u++) {
            float e = *(const float*)(ssc + (((unsigned)ss[u] << SHS) + hb4)) + sdh;
            e = (e > 0.f) ? e : 0.2f * e;
            aa[u] *= __expf(e - mh);
        }
#pragma unroll
        for (int u = 0; u < UNR; u++) {
            const unsigned* p = (const unsigned*)&hv[u];
#pragma unroll
            for (int q = 0; q < 4; q++) {
                acc[2 * q]     += aa[u] * __uint_as_float(p[q] << 16);
                acc[2 * q + 1] += aa[u] * __uint_as_float(p[q] & 0xffff0000u);
            }
        }
    }
#pragma unroll
    for (int off = TPE; off < 64; off <<= 1)
#pragma unroll
        for (int j = 0; j < 8; j++) acc[j] += __shfl_xor(acc[j], off);

    float o[8];
#pragma unroll
    for (int j = 0; j < 8; j++) o[j] = acc[j] + bias[c + j];
    if (MODE == 1) {
        float mx = o[0];
#pragma unroll
        for (int j = 1; j < 8; j++) mx = fmaxf(mx, o[j]);
#pragma unroll
        for (int off = 1; off < TPE; off <<= 1) mx = fmaxf(mx, __shfl_xor(mx, off));
        float sm = 0.f;
#pragma unroll
        for (int j = 0; j < 8; j++) sm += __expf(o[j] - mx);
#pragma unroll
        for (int off = 1; off < TPE; off <<= 1) sm += __shfl_xor(sm, off);
        float lg = logf(sm) + mx;
        if (eo != 0) return;
        float4* op = (float4*)(outF + (size_t)n * CH + c);
        op[0] = make_float4(o[0] - lg, o[1] - lg, o[2] - lg, o[3] - lg);
        op[1] = make_float4(o[4] - lg, o[5] - lg, o[6] - lg, o[7] - lg);
    } else {
        if (eo != 0) return;
        union { unsigned short s[8]; uint4 q; } ph, pl;
#pragma unroll
        for (int j = 0; j < 8; j++) {
            float v = (o[j] > 0.f) ? o[j] : expm1f(o[j]);
            ph.s[j] = f2bf(v);
            pl.s[j] = f2bf(v - __uint_as_float((unsigned)ph.s[j] << 16));
        }
        *(uint4*)(outH + (size_t)n * CH + c) = ph.q;
        *(uint4*)(outL + (size_t)n * CH + c) = pl.q;
    }
}

// ================= launch =================

extern "C" void kernel_launch(void* const* d_in, const int* in_sizes, int n_in,
                              void* d_out, int out_size, void* d_ws, size_t ws_size,
                              hipStream_t stream) {
    const float* x   = (const float*)d_in[0];
    const int*   ei  = (const int*)d_in[1];
    const float* W0  = (const float*)d_in[2];
    const float* b0  = (const float*)d_in[3];
    const float* as0 = (const float*)d_in[4];
    const float* ad0 = (const float*)d_in[5];
    const float* W1  = (const float*)d_in[6];
    const float* b1  = (const float*)d_in[7];
    const float* as1 = (const float*)d_in[8];
    const float* ad1 = (const float*)d_in[9];
    const float* W2  = (const float*)d_in[10];
    const float* b2  = (const float*)d_in[11];
    const float* as2 = (const float*)d_in[12];
    const float* ad2 = (const float*)d_in[13];

    int N = in_sizes[0] / IN_DIM;   // 50000
    int E = in_sizes[1] / 2;        // 1600000
    int Et = E + N;
    int NB = (N + 127) >> NB_SH;    // 391

    char* w = (char*)d_ws;
    size_t off = 0;
    auto alloc = [&](size_t bytes) -> void* {
        void* p = w + off;
        off = (off + bytes + 255) & ~(size_t)255;
        return p;
    };
    unsigned short* Qh    = (unsigned short*)alloc((size_t)N * HID * 2);
    unsigned short* Ql    = (unsigned short*)alloc((size_t)N * HID * 2);
    unsigned short* Ab    = (unsigned short*)alloc((size_t)N * HID * 2);
    unsigned short* xh    = (unsigned short*)alloc((size_t)N * IN_DIM * 2);
    unsigned short* xl    = (unsigned short*)alloc((size_t)N * IN_DIM * 2);
    float*          ssrc  = (float*)alloc((size_t)N * HEADS * 4);
    float*          sdst  = (float*)alloc((size_t)N * HEADS * 4);
    int*            rp    = (int*)alloc((size_t)(N + 1) * 4);
    int*            col   = (int*)alloc((size_t)Et * 4);
    int*            H     = (int*)alloc((size_t)NCHUNK_BLKS * NB * 4);
    int*            total = (int*)alloc((size_t)(NB + 1) * 4);
    int*            base  = (int*)alloc((size_t)(NB + 1) * 4);
    int*            ebuf  = (int*)alloc((size_t)Et * 4);
    unsigned short* Wt0h  = (unsigned short*)alloc((size_t)IN_DIM * HID * 2);
    unsigned short* Wt0l  = (unsigned short*)alloc((size_t)IN_DIM * HID * 2);
    unsigned short* Wt1h  = (unsigned short*)alloc((size_t)HID * HID * 2);
    unsigned short* Wt1l  = (unsigned short*)alloc((size_t)HID * HID * 2);
    unsigned short* Wt2h  = (unsigned short*)alloc((size_t)HID * OUTD * 2);
    unsigned short* Wt2l  = (unsigned short*)alloc((size_t)HID * OUTD * 2);

    // ---- prep ----
    prep_w<<<(IN_DIM * HID + 255) / 256, 256, 0, stream>>>(W0, Wt0h, Wt0l, IN_DIM, HID);
    prep_w<<<(HID * HID + 255) / 256, 256, 0, stream>>>(W1, Wt1h, Wt1l, HID, HID);
    prep_w<<<(HID * OUTD + 255) / 256, 256, 0, stream>>>(W2, Wt2h, Wt2l, HID, OUTD);
    int t8 = N * IN_DIM / 8;
    prep_x<<<(t8 + 255) / 256, 256, 0, stream>>>(x, xh, xl, t8);

    // ---- CSR build ----
    int per_blk = (Et + NCHUNK_BLKS - 1) / NCHUNK_BLKS;
    csr_hist<<<NCHUNK_BLKS, 256, 0, stream>>>(ei, H, E, N, NB, per_blk);
    csr_colscan<<<NB, 256, 0, stream>>>(H, total, NB);
    csr_basescan<<<1, 512, 0, stream>>>(total, base, NB);
    csr_partition<<<NCHUNK_BLKS, 256, 0, stream>>>(ei, H, base, ebuf, E, N, per_blk, NB);
    csr_sort<<<NB, 256, 0, stream>>>(ebuf, base, col, rp, N, NB);

    dim3 gm(2, (N + 127) / 128);     // (cols, rows): col-blocks dispatch-adjacent
    dim3 gm2(1, (N + 127) / 128);
    int gg = (N + 3) / 4;

    // ---- Layer 0 ----
    gemm_mfma<128><<<gm, 256, 0, stream>>>(xh, xl, Wt0h, Wt0l, Ab, as0, ad0, ssrc, sdst,
                                           N, IN_DIM, HID, HEADS);
    gat_fused<HID, HEADS, 0, 4><<<gg, 256, 0, stream>>>(Ab, ssrc, sdst, rp, col, b0,
                                                        nullptr, Qh, Ql, N);

    // ---- Layer 1 ----
    gemm_mfma<128><<<gm, 256, 0, stream>>>(Qh, Ql, Wt1h, Wt1l, Ab, as1, ad1, ssrc, sdst,
                                           N, HID, HID, HEADS);
    gat_fused<HID, HEADS, 0, 4><<<gg, 256, 0, stream>>>(Ab, ssrc, sdst, rp, col, b1,
                                                        nullptr, Qh, Ql, N);

    // ---- Layer 2 ----
    gemm_mfma<32><<<gm2, 256, 0, stream>>>(Qh, Ql, Wt2h, Wt2l, Ab, as2, ad2, ssrc, sdst,
                                           N, HID, OUTD, 1);
    gat_fused<OUTD, 1, 1, 2><<<gg, 256, 0, stream>>>(Ab, ssrc, sdst, rp, col, b2,
                                                     (float*)d_out, nullptr, nullptr, N);
}

// Round 13
// 423.896 us; speedup vs baseline: 1.9131x; 1.0452x over previous
//
#include <hip/hip_runtime.h>
#include <hip/hip_bf16.h>
#include <math.h>

#define IN_DIM 128
#define HID    256
#define OUTD   32
#define HEADS  4
#define NB_SH  7               // 128 dst nodes per bucket
#define BUCKET_CAP 6144        // max edges per bucket (avg ~4224)
#define NCHUNK_BLKS 256        // blocks for hist/partition phases

typedef __attribute__((ext_vector_type(8))) short s8v;
typedef __attribute__((ext_vector_type(4))) float f4v;

__device__ inline unsigned short f2bf(float f) {
    union { __hip_bfloat16 b; unsigned short u; } cv;
    cv.b = __float2bfloat16(f);
    return cv.u;
}

// ================= CSR build (bucketed, write-friendly) =================

__global__ __launch_bounds__(256) void csr_hist(const int* __restrict__ ei,
                                                int* __restrict__ H,
                                                int E, int N, int NB, int per_blk) {
    __shared__ int hist[512];
    int t = threadIdx.x;
    for (int i = t; i < NB; i += 256) hist[i] = 0;
    __syncthreads();
    int lo = blockIdx.x * per_blk;
    int hi = min(lo + per_blk, E + N);
    for (int e = lo + t; e < hi; e += 256) {
        int dst = (e < E) ? ei[E + e] : (e - E);
        atomicAdd(&hist[dst >> NB_SH], 1);
    }
    __syncthreads();
    for (int i = t; i < NB; i += 256) H[blockIdx.x * NB + i] = hist[i];
}

__global__ __launch_bounds__(256) void csr_colscan(int* __restrict__ H,
                                                   int* __restrict__ total, int NB) {
    int b = blockIdx.x, t = threadIdx.x;
    int v = H[t * NB + b];
    __shared__ int s[256];
    s[t] = v;
    __syncthreads();
    for (int o = 1; o < 256; o <<= 1) {
        int x = (t >= o) ? s[t - o] : 0;
        __syncthreads();
        s[t] += x;
        __syncthreads();
    }
    H[t * NB + b] = s[t] - v;
    if (t == 255) total[b] = s[255];
}

__global__ void csr_basescan(const int* __restrict__ total, int* __restrict__ base, int NB) {
    __shared__ int s[512];
    int t = threadIdx.x;
    int v = (t < NB) ? total[t] : 0;
    s[t] = v;
    __syncthreads();
    for (int o = 1; o < 512; o <<= 1) {
        int x = (t >= o) ? s[t - o] : 0;
        __syncthreads();
        s[t] += x;
        __syncthreads();
    }
    if (t < NB) base[t] = s[t] - v;
    if (t == NB - 1) base[NB] = s[t];
}

// packed edge: src (16 bits, N<65536) | (dst&127) << 16
__global__ __launch_bounds__(256) void csr_partition(const int* __restrict__ ei,
                                                     const int* __restrict__ H,
                                                     const int* __restrict__ base,
                                                     int* __restrict__ ebuf,
                                                     int E, int N, int per_blk, int NB) {
    __shared__ int cur[512];
    int t = threadIdx.x;
    for (int i = t; i < NB; i += 256) cur[i] = base[i] + H[blockIdx.x * NB + i];
    __syncthreads();
    int lo = blockIdx.x * per_blk;
    int hi = min(lo + per_blk, E + N);
    for (int e = lo + t; e < hi; e += 256) {
        int src = (e < E) ? ei[e] : (e - E);
        int dst = (e < E) ? ei[E + e] : (e - E);
        int pos = atomicAdd(&cur[dst >> NB_SH], 1);
        ebuf[pos] = src | ((dst & 127) << 16);
    }
}

__global__ __launch_bounds__(256) void csr_sort(const int* __restrict__ ebuf,
                                                const int* __restrict__ base,
                                                int* __restrict__ col,
                                                int* __restrict__ rp, int N, int NB) {
    int b = blockIdx.x, t = threadIdx.x;
    int lo = base[b], hi = base[b + 1];
    int nbase = b << NB_SH;
    __shared__ int c_[128], sc[128], cur[128];
    __shared__ int loc[BUCKET_CAP];
    if (t < 128) c_[t] = 0;
    __syncthreads();
    for (int k = lo + t; k < hi; k += 256) atomicAdd(&c_[(ebuf[k] >> 16) & 127], 1);
    __syncthreads();
    if (t < 128) sc[t] = c_[t];
    __syncthreads();
    for (int o = 1; o < 128; o <<= 1) {
        int x = 0;
        if (t < 128 && t >= o) x = sc[t - o];
        __syncthreads();
        if (t < 128) sc[t] += x;
        __syncthreads();
    }
    if (t < 128) {
        int excl = sc[t] - c_[t];
        cur[t] = excl;
        int node = nbase + t;
        if (node < N) rp[node] = lo + excl;
    }
    if (b == NB - 1 && t == 0) rp[N] = hi;
    __syncthreads();
    for (int k = lo + t; k < hi; k += 256) {
        int e = ebuf[k];
        int p = atomicAdd(&cur[(e >> 16) & 127], 1);
        if (p < BUCKET_CAP) loc[p] = e & 0xFFFF;
    }
    __syncthreads();
    int m = min(hi - lo, BUCKET_CAP);
    for (int k = t; k < m; k += 256) col[lo + k] = loc[k];
}

// ================= prep: f32 -> hi/lo bf16 =================

__global__ __launch_bounds__(256) void prep_w(const float* __restrict__ W,
                                              unsigned short* __restrict__ Wt_h,
                                              unsigned short* __restrict__ Wt_l,
                                              int K, int N) {
    int idx = blockIdx.x * 256 + threadIdx.x;
    if (idx >= K * N) return;
    int n = idx / K, k = idx % K;
    float x = W[(size_t)k * N + n];
    unsigned short h = f2bf(x);
    float hf = __uint_as_float((unsigned)h << 16);
    Wt_h[idx] = h;
    Wt_l[idx] = f2bf(x - hf);
}

__global__ __launch_bounds__(256) void prep_x(const float* __restrict__ X,
                                              unsigned short* __restrict__ Xh,
                                              unsigned short* __restrict__ Xl,
                                              int total8) {
    int idx = blockIdx.x * 256 + threadIdx.x;
    if (idx >= total8) return;
    size_t b = (size_t)idx * 8;
    float4 v0 = *(const float4*)(X + b);
    float4 v1 = *(const float4*)(X + b + 4);
    float x[8] = {v0.x, v0.y, v0.z, v0.w, v1.x, v1.y, v1.z, v1.w};
    union { unsigned short s[8]; uint4 q; } h, l;
#pragma unroll
    for (int j = 0; j < 8; j++) {
        h.s[j] = f2bf(x[j]);
        l.s[j] = f2bf(x[j] - __uint_as_float((unsigned)h.s[j] << 16));
    }
    *(uint4*)(Xh + b) = h.q;
    *(uint4*)(Xl + b) = l.q;
}

// ================= MFMA GEMM (hi/lo bf16) + fused scores =================
// Tile 64 rows x BN cols, BK=32. BN=128: 4 waves as 2x2 of 32x64 (grid ~1564
// blocks -> ~6 blocks/CU). BN=32: 4 waves as 4x1 of 16x32. LDS 24/12 KB.

template <int BN>
__global__ __launch_bounds__(256, 2) void gemm_mfma(const unsigned short* __restrict__ Ah,
                                                    const unsigned short* __restrict__ Al,
                                                    const unsigned short* __restrict__ Wt_h,
                                                    const unsigned short* __restrict__ Wt_l,
                                                    unsigned short* __restrict__ Cb,
                                                    const float* __restrict__ asrc,
                                                    const float* __restrict__ adst,
                                                    float* __restrict__ ssrcO,
                                                    float* __restrict__ sdstO,
                                                    int M, int K, int Nst, int Hn) {
    constexpr int WROWS = (BN == 128) ? 32 : 16;
    constexpr int WCOLS = (BN == 128) ? 64 : 32;
    constexpr int MI = WROWS / 16, NJ = WCOLS / 16;
    __shared__ unsigned short As_h[64][32], As_l[64][32];     // 8 KB
    __shared__ unsigned short Bs_h[BN][32], Bs_l[BN][32];     // 16 or 4 KB
    int tid = threadIdx.x;
    int lane = tid & 63, w = tid >> 6;
    int wm, wn;
    if (BN == 128) { wm = w & 1; wn = w >> 1; } else { wm = w; wn = 0; }
    int row0 = blockIdx.y * 64, col0 = blockIdx.x * BN;
    int lr = lane & 15;

    f4v acc[MI][NJ];
#pragma unroll
    for (int i = 0; i < MI; i++)
#pragma unroll
        for (int j = 0; j < NJ; j++) acc[i][j] = (f4v)(0.f);

    for (int k0 = 0; k0 < K; k0 += 32) {
        // ---- stage A: 64 rows x 4 chunks = 256 chunks, 1 per thread ----
        {
            int c = tid;
            int r = c >> 2, ch = c & 3;
            int grow = row0 + r;
            uint4 vh = make_uint4(0, 0, 0, 0), vl = make_uint4(0, 0, 0, 0);
            if (grow < M) {
                size_t g = (size_t)grow * K + k0 + ch * 8;
                vh = *(const uint4*)(Ah + g);
                vl = *(const uint4*)(Al + g);
            }
            int chs = ch ^ ((r >> 1) & 3);
            *(uint4*)&As_h[r][chs * 8] = vh;
            *(uint4*)&As_l[r][chs * 8] = vl;
        }
        // ---- stage B: BN rows x 4 chunks ----
        for (int c = tid; c < BN * 4; c += 256) {
            int n = c >> 2, ch = c & 3;
            int chs = ch ^ ((n >> 1) & 3);
            size_t g = (size_t)(col0 + n) * K + k0 + ch * 8;
            *(uint4*)&Bs_h[n][chs * 8] = *(const uint4*)(Wt_h + g);
            *(uint4*)&Bs_l[n][chs * 8] = *(const uint4*)(Wt_l + g);
        }
        __syncthreads();
        {
            int kc = lane >> 4;   // 0..3 covers BK=32
            s8v ah[MI], al[MI], bh[NJ], bl[NJ];
#pragma unroll
            for (int i = 0; i < MI; i++) {
                int r = wm * WROWS + i * 16 + lr;
                int chs = kc ^ ((r >> 1) & 3);
                ah[i] = *(const s8v*)&As_h[r][chs * 8];
                al[i] = *(const s8v*)&As_l[r][chs * 8];
            }
#pragma unroll
            for (int j = 0; j < NJ; j++) {
                int n = wn * WCOLS + j * 16 + lr;
                int chs = kc ^ ((n >> 1) & 3);
                bh[j] = *(const s8v*)&Bs_h[n][chs * 8];
                bl[j] = *(const s8v*)&Bs_l[n][chs * 8];
            }
#pragma unroll
            for (int i = 0; i < MI; i++)
#pragma unroll
                for (int j = 0; j < NJ; j++) {
                    acc[i][j] = __builtin_amdgcn_mfma_f32_16x16x32_bf16(ah[i], bh[j], acc[i][j], 0, 0, 0);
                    acc[i][j] = __builtin_amdgcn_mfma_f32_16x16x32_bf16(ah[i], bl[j], acc[i][j], 0, 0, 0);
                    acc[i][j] = __builtin_amdgcn_mfma_f32_16x16x32_bf16(al[i], bh[j], acc[i][j], 0, 0, 0);
                }
        }
        __syncthreads();
    }
    int lg = lane >> 4;
#pragma unroll
    for (int i = 0; i < MI; i++)
#pragma unroll
        for (int j = 0; j < NJ; j++) {
            int gcol = col0 + wn * WCOLS + j * 16 + lr;
#pragma unroll
            for (int rr = 0; rr < 4; rr++) {
                int grow = row0 + wm * WROWS + i * 16 + lg * 4 + rr;
                if (grow < M) Cb[(size_t)grow * Nst + gcol] = f2bf(acc[i][j][rr]);
            }
        }
    // ---- fused scores: this wave owns head hd entirely (WCOLS == D) ----
    int hd = (BN == 128) ? (blockIdx.x * 2 + wn) : 0;
    float as_[NJ], ad_[NJ];
#pragma unroll
    for (int j = 0; j < NJ; j++) {
        int gcol = col0 + wn * WCOLS + j * 16 + lr;
        as_[j] = asrc[gcol];
        ad_[j] = adst[gcol];
    }
#pragma unroll
    for (int i = 0; i < MI; i++)
#pragma unroll
        for (int rr = 0; rr < 4; rr++) {
            float ps = 0.f, pd = 0.f;
#pragma unroll
            for (int j = 0; j < NJ; j++) {
                ps += acc[i][j][rr] * as_[j];
                pd += acc[i][j][rr] * ad_[j];
            }
#pragma unroll
            for (int off = 1; off < 16; off <<= 1) {
                ps += __shfl_xor(ps, off);
                pd += __shfl_xor(pd, off);
            }
            int grow = row0 + wm * WROWS + i * 16 + lg * 4 + rr;
            if (lr == 0 && grow < M) {
                ssrcO[(size_t)grow * Hn + hd] = ps;
                sdstO[(size_t)grow * Hn + hd] = pd;
            }
        }
}

// ================= fused segment-softmax + weighted gather (measured 124us, unchanged) =================

template <int CH, int H, int MODE, int UNR>
__global__ __launch_bounds__(256) void gat_fused(const unsigned short* __restrict__ hb,
                                                 const float* __restrict__ ssrc,
                                                 const float* __restrict__ sdst,
                                                 const int* __restrict__ rp,
                                                 const int* __restrict__ col,
                                                 const float* __restrict__ bias,
                                                 float* __restrict__ outF,
                                                 unsigned short* __restrict__ outH,
                                                 unsigned short* __restrict__ outL, int N) {
    const int TPE = CH / 8;
    const int EPW = 64 / TPE;
    const int D = CH / H;
    constexpr int SHCH = (CH == 256) ? 9 : 6;
    constexpr int SHS = (H == 4) ? 4 : 2;
    int wv = threadIdx.x >> 6, lane = threadIdx.x & 63;
    int n = blockIdx.x * 4 + wv;
    if (n >= N) return;
    int k0 = __builtin_amdgcn_readfirstlane(rp[n]);
    int k1 = __builtin_amdgcn_readfirstlane(rp[n + 1]);

    int h1 = lane % H;
    int slot = lane / H;
    const int SL = 64 / H;
    float sd1 = sdst[(size_t)n * H + h1];
    float m = -1e30f, l = 0.f;
    for (int k = k0 + slot; k < k1; k += SL) {
        int s = col[k];
        float e = ssrc[(size_t)s * H + h1] + sd1;
        e = (e > 0.f) ? e : 0.2f * e;
        float mn = fmaxf(m, e);
        l = l * __expf(m - mn) + __expf(e - mn);
        m = mn;
    }
#pragma unroll
    for (int off = H; off < 64; off <<= 1) {
        float m2 = __shfl_xor(m, off);
        float l2 = __shfl_xor(l, off);
        float mn = fmaxf(m, m2);
        l = l * __expf(m - mn) + l2 * __expf(m2 - mn);
        m = mn;
    }

    int eo = lane / TPE;
    int c = (lane % TPE) * 8;
    int head = c / D;
    float mh = __shfl(m, head);
    float invl = 1.f / __shfl(l, head);
    float sdh = __shfl(sd1, head);

    const char* hbc = (const char*)hb;
    const char* ssc = (const char*)ssrc;
    unsigned cb = (unsigned)(c << 1);
    unsigned hb4 = (unsigned)(head << 2);

    float acc[8];
#pragma unroll
    for (int j = 0; j < 8; j++) acc[j] = 0.f;

    for (int k = k0; k < k1; k += UNR * EPW) {
        int ss[UNR];
        float aa[UNR];
#pragma unroll
        for (int u = 0; u < UNR; u++) {
            int ku = k + u * EPW + eo;
            bool v = ku < k1;
            ss[u] = col[v ? ku : k0];
            aa[u] = v ? invl : 0.f;
        }
        uint4 hv[UNR];
#pragma unroll
        for (int u = 0; u < UNR; u++)
            hv[u] = *(const uint4*)(hbc + (((unsigned)ss[u] << SHCH) + cb));
#pragma unroll
        for (int u = 0; u < UNR; u++) {
            float e = *(const float*)(ssc + (((unsigned)ss[u] << SHS) + hb4)) + sdh;
            e = (e > 0.f) ? e : 0.2f * e;
            aa[u] *= __expf(e - mh);
        }
#pragma unroll
        for (int u = 0; u < UNR; u++) {
            const unsigned* p = (const unsigned*)&hv[u];
#pragma unroll
            for (int q = 0; q < 4; q++) {
                acc[2 * q]     += aa[u] * __uint_as_float(p[q] << 16);
                acc[2 * q + 1] += aa[u] * __uint_as_float(p[q] & 0xffff0000u);
            }
        }
    }
#pragma unroll
    for (int off = TPE; off < 64; off <<= 1)
#pragma unroll
        for (int j = 0; j < 8; j++) acc[j] += __shfl_xor(acc[j], off);

    float o[8];
#pragma unroll
    for (int j = 0; j < 8; j++) o[j] = acc[j] + bias[c + j];
    if (MODE == 1) {
        float mx = o[0];
#pragma unroll
        for (int j = 1; j < 8; j++) mx = fmaxf(mx, o[j]);
#pragma unroll
        for (int off = 1; off < TPE; off <<= 1) mx = fmaxf(mx, __shfl_xor(mx, off));
        float sm = 0.f;
#pragma unroll
        for (int j = 0; j < 8; j++) sm += __expf(o[j] - mx);
#pragma unroll
        for (int off = 1; off < TPE; off <<= 1) sm += __shfl_xor(sm, off);
        float lg = logf(sm) + mx;
        if (eo != 0) return;
        float4* op = (float4*)(outF + (size_t)n * CH + c);
        op[0] = make_float4(o[0] - lg, o[1] - lg, o[2] - lg, o[3] - lg);
        op[1] = make_float4(o[4] - lg, o[5] - lg, o[6] - lg, o[7] - lg);
    } else {
        if (eo != 0) return;
        union { unsigned short s[8]; uint4 q; } ph, pl;
#pragma unroll
        for (int j = 0; j < 8; j++) {
            float v = (o[j] > 0.f) ? o[j] : expm1f(o[j]);
            ph.s[j] = f2bf(v);
            pl.s[j] = f2bf(v - __uint_as_float((unsigned)ph.s[j] << 16));
        }
        *(uint4*)(outH + (size_t)n * CH + c) = ph.q;
        *(uint4*)(outL + (size_t)n * CH + c) = pl.q;
    }
}

// ================= launch =================

extern "C" void kernel_launch(void* const* d_in, const int* in_sizes, int n_in,
                              void* d_out, int out_size, void* d_ws, size_t ws_size,
                              hipStream_t stream) {
    const float* x   = (const float*)d_in[0];
    const int*   ei  = (const int*)d_in[1];
    const float* W0  = (const float*)d_in[2];
    const float* b0  = (const float*)d_in[3];
    const float* as0 = (const float*)d_in[4];
    const float* ad0 = (const float*)d_in[5];
    const float* W1  = (const float*)d_in[6];
    const float* b1  = (const float*)d_in[7];
    const float* as1 = (const float*)d_in[8];
    const float* ad1 = (const float*)d_in[9];
    const float* W2  = (const float*)d_in[10];
    const float* b2  = (const float*)d_in[11];
    const float* as2 = (const float*)d_in[12];
    const float* ad2 = (const float*)d_in[13];

    int N = in_sizes[0] / IN_DIM;   // 50000
    int E = in_sizes[1] / 2;        // 1600000
    int Et = E + N;
    int NB = (N + 127) >> NB_SH;    // 391

    char* w = (char*)d_ws;
    size_t off = 0;
    auto alloc = [&](size_t bytes) -> void* {
        void* p = w + off;
        off = (off + bytes + 255) & ~(size_t)255;
        return p;
    };
    unsigned short* Qh    = (unsigned short*)alloc((size_t)N * HID * 2);
    unsigned short* Ql    = (unsigned short*)alloc((size_t)N * HID * 2);
    unsigned short* Ab    = (unsigned short*)alloc((size_t)N * HID * 2);
    unsigned short* xh    = (unsigned short*)alloc((size_t)N * IN_DIM * 2);
    unsigned short* xl    = (unsigned short*)alloc((size_t)N * IN_DIM * 2);
    float*          ssrc  = (float*)alloc((size_t)N * HEADS * 4);
    float*          sdst  = (float*)alloc((size_t)N * HEADS * 4);
    int*            rp    = (int*)alloc((size_t)(N + 1) * 4);
    int*            col   = (int*)alloc((size_t)Et * 4);
    int*            H     = (int*)alloc((size_t)NCHUNK_BLKS * NB * 4);
    int*            total = (int*)alloc((size_t)(NB + 1) * 4);
    int*            base  = (int*)alloc((size_t)(NB + 1) * 4);
    int*            ebuf  = (int*)alloc((size_t)Et * 4);
    unsigned short* Wt0h  = (unsigned short*)alloc((size_t)IN_DIM * HID * 2);
    unsigned short* Wt0l  = (unsigned short*)alloc((size_t)IN_DIM * HID * 2);
    unsigned short* Wt1h  = (unsigned short*)alloc((size_t)HID * HID * 2);
    unsigned short* Wt1l  = (unsigned short*)alloc((size_t)HID * HID * 2);
    unsigned short* Wt2h  = (unsigned short*)alloc((size_t)HID * OUTD * 2);
    unsigned short* Wt2l  = (unsigned short*)alloc((size_t)HID * OUTD * 2);

    // ---- prep ----
    prep_w<<<(IN_DIM * HID + 255) / 256, 256, 0, stream>>>(W0, Wt0h, Wt0l, IN_DIM, HID);
    prep_w<<<(HID * HID + 255) / 256, 256, 0, stream>>>(W1, Wt1h, Wt1l, HID, HID);
    prep_w<<<(HID * OUTD + 255) / 256, 256, 0, stream>>>(W2, Wt2h, Wt2l, HID, OUTD);
    int t8 = N * IN_DIM / 8;
    prep_x<<<(t8 + 255) / 256, 256, 0, stream>>>(x, xh, xl, t8);

    // ---- CSR build ----
    int per_blk = (Et + NCHUNK_BLKS - 1) / NCHUNK_BLKS;
    csr_hist<<<NCHUNK_BLKS, 256, 0, stream>>>(ei, H, E, N, NB, per_blk);
    csr_colscan<<<NB, 256, 0, stream>>>(H, total, NB);
    csr_basescan<<<1, 512, 0, stream>>>(total, base, NB);
    csr_partition<<<NCHUNK_BLKS, 256, 0, stream>>>(ei, H, base, ebuf, E, N, per_blk, NB);
    csr_sort<<<NB, 256, 0, stream>>>(ebuf, base, col, rp, N, NB);

    dim3 gm(2, (N + 63) / 64);      // 1564 blocks -> ~6 blocks/CU
    dim3 gm2(1, (N + 63) / 64);
    int gg = (N + 3) / 4;

    // ---- Layer 0 ----
    gemm_mfma<128><<<gm, 256, 0, stream>>>(xh, xl, Wt0h, Wt0l, Ab, as0, ad0, ssrc, sdst,
                                           N, IN_DIM, HID, HEADS);
    gat_fused<HID, HEADS, 0, 4><<<gg, 256, 0, stream>>>(Ab, ssrc, sdst, rp, col, b0,
                                                        nullptr, Qh, Ql, N);

    // ---- Layer 1 ----
    gemm_mfma<128><<<gm, 256, 0, stream>>>(Qh, Ql, Wt1h, Wt1l, Ab, as1, ad1, ssrc, sdst,
                                           N, HID, HID, HEADS);
    gat_fused<HID, HEADS, 0, 4><<<gg, 256, 0, stream>>>(Ab, ssrc, sdst, rp, col, b1,
                                                        nullptr, Qh, Ql, N);

    // ---- Layer 2 ----
    gemm_mfma<32><<<gm2, 256, 0, stream>>>(Qh, Ql, Wt2h, Wt2l, Ab, as2, ad2, ssrc, sdst,
                                           N, HID, OUTD, 1);
    gat_fused<OUTD, 1, 1, 2><<<gg, 256, 0, stream>>>(Ab, ssrc, sdst, rp, col, b2,
                                                     (float*)d_out, nullptr, nullptr, N);
}